// Round 6
// baseline (774.111 us; speedup 1.0000x reference)
//
#include <hip/hip_runtime.h>
#include <math.h>

// Problem constants (reference is fixed): VOCAB known; T, B, S derived from sizes.
#define VOCAB 128000

constexpr int NVEC      = VOCAB / 4;     // 32000 float4 per row
constexpr int PARTS     = 2;             // blocks per row -> 2304 blocks = 9/CU exactly
constexpr int NVEC_PART = NVEC / PARTS;  // 16000 float4 per block
constexpr int BLK       = 256;

// ---------------- Kernel 1: per-(row,part) argmax partials ----------------
// First-occurrence tie-break (matches jnp.argmax): per-thread strided scan is
// index-increasing with '>' (keeps earliest); cross-thread reduce prefers the
// lower index on equal value.
__global__ __launch_bounds__(BLK) void argmax_part_kernel(
    const float* __restrict__ logits,
    float* __restrict__ pval,
    int*   __restrict__ pidx)
{
    const int row  = blockIdx.x / PARTS;
    const int part = blockIdx.x % PARTS;
    const float4* rp = reinterpret_cast<const float4*>(logits)
                       + (size_t)row * NVEC + (size_t)part * NVEC_PART;

    float best = -INFINITY;
    int   bidx = 0;
    for (int i = threadIdx.x; i < NVEC_PART; i += BLK) {
        const float4 v = rp[i];                       // coalesced 16B/lane
        const int base = (part * NVEC_PART + i) * 4;  // global column index
        if (v.x > best) { best = v.x; bidx = base;     }
        if (v.y > best) { best = v.y; bidx = base + 1; }
        if (v.z > best) { best = v.z; bidx = base + 2; }
        if (v.w > best) { best = v.w; bidx = base + 3; }
    }

    // wave-64 down-reduce; prefer lower index on equal value
    #pragma unroll
    for (int off = 32; off > 0; off >>= 1) {
        const float ov = __shfl_down(best, off, 64);
        const int   oi = __shfl_down(bidx, off, 64);
        if (ov > best || (ov == best && oi < bidx)) { best = ov; bidx = oi; }
    }

    __shared__ float sv[BLK / 64];
    __shared__ int   si[BLK / 64];
    const int lane = threadIdx.x & 63;
    const int wid  = threadIdx.x >> 6;
    if (lane == 0) { sv[wid] = best; si[wid] = bidx; }
    __syncthreads();
    if (threadIdx.x == 0) {
        best = sv[0]; bidx = si[0];
        #pragma unroll
        for (int w = 1; w < BLK / 64; ++w) {
            if (sv[w] > best || (sv[w] == best && si[w] < bidx)) {
                best = sv[w]; bidx = si[w];
            }
        }
        pval[blockIdx.x] = best;
        pidx[blockIdx.x] = bidx;
    }
}

// ---------------- Kernel 2: per-sequence rejection logic ----------------
// One thread per sequence (B==256). Output dtype is INT32 (harness reads
// integer-output references as np.int32 then converts to f32 for compare).
__global__ __launch_bounds__(BLK) void reject_kernel(
    const float* __restrict__ pval,
    const int*   __restrict__ pidx,
    const int*   __restrict__ draft,
    const int*   __restrict__ bonus,
    const int*   __restrict__ ndraft,
    int*         __restrict__ out,
    int B, int S)
{
    __shared__ int n_lds[BLK];
    const int b = threadIdx.x;
    const int n = (b < B) ? ndraft[b] : 0;
    n_lds[b] = n;
    __syncthreads();
    if (b >= B) return;

    // ragged offset cu[b] = sum_{i<b} n[i]  (LDS broadcast reads — trivial)
    int cu = 0;
    for (int i = 0; i < b; ++i) cu += n_lds[i];

    // target argmax per owned token: combine the PARTS partials.
    int am[8];  // n <= S <= 8 for this problem
    for (int s = 0; s < n; ++s) {
        const int t = cu + s;
        float v0 = pval[t * PARTS + 0];
        int   i0 = pidx[t * PARTS + 0];
        #pragma unroll
        for (int p = 1; p < PARTS; ++p) {
            const float vp = pval[t * PARTS + p];
            const int   ip = pidx[t * PARTS + p];
            if (vp > v0 || (vp == v0 && ip < i0)) { v0 = vp; i0 = ip; }
        }
        am[s] = i0;
    }

    // leading-match count
    int num_accept = 0;
    for (int s = 0; s < n; ++s) {
        if (num_accept == s && am[s] == draft[cu + s]) num_accept = s + 1;
    }
    const bool rejected  = num_accept < n;
    const int  write_len = rejected ? num_accept + 1 : n;   // <= n <= S

    // out[b, 0..S]
    for (int s = 0; s <= S; ++s) {
        int v = -1;
        if (s < write_len) v = am[s];                 // s < write_len <= n
        if (s == n && !rejected) v = bonus[b];
        out[b * (S + 1) + s] = v;
    }
    // num_rejected_tokens[b]
    out[B * (S + 1) + b] = n - num_accept;
    // last_token_ids[b]: first mismatch's target argmax if rejected, else bonus
    out[B * (S + 1) + B + b] = rejected ? am[num_accept] : bonus[b];
}

extern "C" void kernel_launch(void* const* d_in, const int* in_sizes, int n_in,
                              void* d_out, int out_size, void* d_ws, size_t ws_size,
                              hipStream_t stream)
{
    const float* logits = (const float*)d_in[0];   // [T, VOCAB] fp32
    const int*   draft  = (const int*)d_in[1];     // [T]
    const int*   bonus  = (const int*)d_in[2];     // [B]
    const int*   ndraft = (const int*)d_in[3];     // [B]
    // d_in[4] = max_spec_num scalar (device); S derived on host instead.

    const int T = in_sizes[1];              // num_tokens (1152)
    const int B = in_sizes[2];              // batch (256)
    const int S = out_size / B - 3;         // out_size = B*(S+1) + B + B

    float* pval = (float*)d_ws;
    int*   pidx = (int*)((char*)d_ws + sizeof(float) * (size_t)T * PARTS);

    argmax_part_kernel<<<T * PARTS, BLK, 0, stream>>>(logits, pval, pidx);
    reject_kernel<<<1, BLK, 0, stream>>>(pval, pidx, draft, bonus, ndraft,
                                         (int*)d_out, B, S);
}

// Round 7
// 755.135 us; speedup vs baseline: 1.0251x; 1.0251x over previous
//
#include <hip/hip_runtime.h>
#include <math.h>

// Problem constants (reference is fixed): VOCAB known; T, B, S derived from sizes.
#define VOCAB 128000

constexpr int NVEC      = VOCAB / 4;          // 32000 float4 per row
constexpr int PARTS     = 2;                  // blocks per row -> 2304 blocks
constexpr int NVEC_PART = NVEC / PARTS;       // 16000 float4 per block
constexpr int BLK       = 256;
constexpr int NPAIR     = NVEC_PART / (2 * BLK);   // 31 full paired iterations
constexpr int TAIL0     = NPAIR * 2 * BLK;         // 15872
constexpr int NTAIL     = NVEC_PART - TAIL0;       // 128 (threads 0..127 do one extra)

// ---------------- Kernel 1: per-(row,part) argmax partials ----------------
// First-occurrence tie-break (matches jnp.argmax): each chain is
// index-increasing with '>' (keeps earliest); every merge (chain/lane/wave)
// prefers the lower index on equal value.
__global__ __launch_bounds__(BLK) void argmax_part_kernel(
    const float* __restrict__ logits,
    float* __restrict__ pval,
    int*   __restrict__ pidx)
{
    const int row  = blockIdx.x / PARTS;
    const int part = blockIdx.x % PARTS;
    const float4* rp = reinterpret_cast<const float4*>(logits)
                       + (size_t)row * NVEC + (size_t)part * NVEC_PART;
    const int cb = part * NVEC_PART * 4;      // global column base of this part

    // two independent compare chains -> 2x outstanding dwordx4 loads
    float b0 = -INFINITY, b1 = -INFINITY;
    int   i0 = 0,          i1 = 0;

    int i = threadIdx.x;
    #pragma unroll 4
    for (int k = 0; k < NPAIR; ++k, i += 2 * BLK) {
        const float4 va = rp[i];
        const float4 vb = rp[i + BLK];
        const int ca = cb + i * 4;
        const int cc = ca + BLK * 4;
        if (va.x > b0) { b0 = va.x; i0 = ca;     }
        if (va.y > b0) { b0 = va.y; i0 = ca + 1; }
        if (va.z > b0) { b0 = va.z; i0 = ca + 2; }
        if (va.w > b0) { b0 = va.w; i0 = ca + 3; }
        if (vb.x > b1) { b1 = vb.x; i1 = cc;     }
        if (vb.y > b1) { b1 = vb.y; i1 = cc + 1; }
        if (vb.z > b1) { b1 = vb.z; i1 = cc + 2; }
        if (vb.w > b1) { b1 = vb.w; i1 = cc + 3; }
    }
    if (threadIdx.x < NTAIL) {                 // ragged 0.5 iteration, chain 0
        const float4 va = rp[TAIL0 + threadIdx.x];
        const int ca = cb + (TAIL0 + threadIdx.x) * 4;
        if (va.x > b0) { b0 = va.x; i0 = ca;     }
        if (va.y > b0) { b0 = va.y; i0 = ca + 1; }
        if (va.z > b0) { b0 = va.z; i0 = ca + 2; }
        if (va.w > b0) { b0 = va.w; i0 = ca + 3; }
    }
    // merge chains (indices interleave -> min-index on tie)
    if (b1 > b0 || (b1 == b0 && i1 < i0)) { b0 = b1; i0 = i1; }

    float best = b0;
    int   bidx = i0;

    // wave-64 down-reduce; prefer lower index on equal value
    #pragma unroll
    for (int off = 32; off > 0; off >>= 1) {
        const float ov = __shfl_down(best, off, 64);
        const int   oi = __shfl_down(bidx, off, 64);
        if (ov > best || (ov == best && oi < bidx)) { best = ov; bidx = oi; }
    }

    __shared__ float sv[BLK / 64];
    __shared__ int   si[BLK / 64];
    const int lane = threadIdx.x & 63;
    const int wid  = threadIdx.x >> 6;
    if (lane == 0) { sv[wid] = best; si[wid] = bidx; }
    __syncthreads();
    if (threadIdx.x == 0) {
        best = sv[0]; bidx = si[0];
        #pragma unroll
        for (int w = 1; w < BLK / 64; ++w) {
            if (sv[w] > best || (sv[w] == best && si[w] < bidx)) {
                best = sv[w]; bidx = si[w];
            }
        }
        pval[blockIdx.x] = best;
        pidx[blockIdx.x] = bidx;
    }
}

// ---------------- Kernel 2: per-sequence rejection logic ----------------
// One thread per sequence (B==256). Output dtype is INT32 (harness reads
// integer-output references as np.int32 then converts to f32 for compare).
__global__ __launch_bounds__(BLK) void reject_kernel(
    const float* __restrict__ pval,
    const int*   __restrict__ pidx,
    const int*   __restrict__ draft,
    const int*   __restrict__ bonus,
    const int*   __restrict__ ndraft,
    int*         __restrict__ out,
    int B, int S)
{
    __shared__ int n_lds[BLK];
    const int b = threadIdx.x;
    const int n = (b < B) ? ndraft[b] : 0;
    n_lds[b] = n;
    __syncthreads();
    if (b >= B) return;

    // ragged offset cu[b] = sum_{i<b} n[i]  (LDS broadcast reads — trivial)
    int cu = 0;
    for (int i = 0; i < b; ++i) cu += n_lds[i];

    // target argmax per owned token: combine the PARTS partials.
    int am[8];  // n <= S <= 8 for this problem
    for (int s = 0; s < n; ++s) {
        const int t = cu + s;
        float v0 = pval[t * PARTS + 0];
        int   j0 = pidx[t * PARTS + 0];
        #pragma unroll
        for (int p = 1; p < PARTS; ++p) {
            const float vp = pval[t * PARTS + p];
            const int   jp = pidx[t * PARTS + p];
            if (vp > v0 || (vp == v0 && jp < j0)) { v0 = vp; j0 = jp; }
        }
        am[s] = j0;
    }

    // leading-match count
    int num_accept = 0;
    for (int s = 0; s < n; ++s) {
        if (num_accept == s && am[s] == draft[cu + s]) num_accept = s + 1;
    }
    const bool rejected  = num_accept < n;
    const int  write_len = rejected ? num_accept + 1 : n;   // <= n <= S

    // out[b, 0..S]
    for (int s = 0; s <= S; ++s) {
        int v = -1;
        if (s < write_len) v = am[s];                 // s < write_len <= n
        if (s == n && !rejected) v = bonus[b];
        out[b * (S + 1) + s] = v;
    }
    // num_rejected_tokens[b]
    out[B * (S + 1) + b] = n - num_accept;
    // last_token_ids[b]: first mismatch's target argmax if rejected, else bonus
    out[B * (S + 1) + B + b] = rejected ? am[num_accept] : bonus[b];
}

extern "C" void kernel_launch(void* const* d_in, const int* in_sizes, int n_in,
                              void* d_out, int out_size, void* d_ws, size_t ws_size,
                              hipStream_t stream)
{
    const float* logits = (const float*)d_in[0];   // [T, VOCAB] fp32
    const int*   draft  = (const int*)d_in[1];     // [T]
    const int*   bonus  = (const int*)d_in[2];     // [B]
    const int*   ndraft = (const int*)d_in[3];     // [B]
    // d_in[4] = max_spec_num scalar (device); S derived on host instead.

    const int T = in_sizes[1];              // num_tokens (1152)
    const int B = in_sizes[2];              // batch (256)
    const int S = out_size / B - 3;         // out_size = B*(S+1) + B + B

    float* pval = (float*)d_ws;
    int*   pidx = (int*)((char*)d_ws + sizeof(float) * (size_t)T * PARTS);

    argmax_part_kernel<<<T * PARTS, BLK, 0, stream>>>(logits, pval, pidx);
    reject_kernel<<<1, BLK, 0, stream>>>(pval, pidx, draft, bonus, ndraft,
                                         (int*)d_out, B, S);
}